// Round 7
// baseline (448.600 us; speedup 1.0000x reference)
//
#include <hip/hip_runtime.h>
#include <hip/hip_bf16.h>

typedef __hip_bfloat16 bf16h;
typedef short bf16x8 __attribute__((ext_vector_type(8)));
typedef float f32x4 __attribute__((ext_vector_type(4)));

#define NH 12
#define CHD 16
#define PQN 4
#define PVN 8
#define CSD 384
#define CZD 128
#define NN 512
#define HC 192
#define OUTD 2112
#define NSQ (NN*NN)
#define NPROJ 1152

// ws layout (float offsets). a aliases proj scratch (stream-ordered, safe).
#define OFF_Q    0u
#define OFF_K    98304u
#define OFF_V    196608u
#define OFF_QP   294912u
#define OFF_KP   368640u
#define OFF_VP   442368u
#define OFF_A    589824u
#define OFF_RAW  589824u     /* f32 512x1152 = 589824 floats -> ends 1179648 */
#define OFF_SB   1179648u    /* bf16 512x384  = 98304 floats -> ends 1277952 */
#define OFF_WCT  1277952u    /* bf16 1152x384 = 221184 floats -> ends 1499136 (< 3735552 OK) */
#define OFF_CATB 3735552u    /* bf16 512x2112 = 540672 floats */
#define OFF_WOT  4276224u    /* bf16 384x2112 = 405504 floats */
#define OFF_BCAT 4681728u    /* f32 1152 -> end 4682880 floats = 18.73 MB */

// ---------------- Kernel W1: pack weights/s to bf16, concat biases ----------------
__global__ __launch_bounds__(256) void k_wcat(
    const float* __restrict__ s,
    const float* __restrict__ Wq, const float* __restrict__ bq,
    const float* __restrict__ Wkv, const float* __restrict__ bkv,
    const float* __restrict__ Wqp, const float* __restrict__ bqp,
    const float* __restrict__ Wkvp, const float* __restrict__ bkvp,
    const float* __restrict__ Wout, float* __restrict__ ws)
{
  const int b = blockIdx.x, t = threadIdx.x;
  if (b < NPROJ) {
    const float* W; int col, ld;
    if (b < 192)      { W = Wq;   col = b;     ld = 192; }
    else if (b < 576) { W = Wkv;  col = b-192; ld = 384; }
    else if (b < 720) { W = Wqp;  col = b-576; ld = 144; }
    else              { W = Wkvp; col = b-720; ld = 432; }
    bf16h* dst = (bf16h*)(ws + OFF_WCT) + (size_t)b*CSD;
    for (int c = t; c < CSD; c += 256) dst[c] = __float2bfloat16(W[c*ld + col]);
  } else if (b < NPROJ + 128) {
    const int n0 = (b - NPROJ)*4;
    bf16h* sb = (bf16h*)(ws + OFF_SB);
    for (int idx = t; idx < 4*CSD; idx += 256)
      sb[(size_t)n0*CSD + idx] = __float2bfloat16(s[(size_t)n0*CSD + idx]);
  } else if (b < NPROJ + 128 + CSD) {
    const int n = b - (NPROJ + 128);
    bf16h* woutT = (bf16h*)(ws + OFF_WOT);
    for (int k = t; k < OUTD; k += 256)
      woutT[(size_t)n*OUTD + k] = __float2bfloat16(Wout[(size_t)k*CSD + n]);
  } else {
    float* bcat = ws + OFF_BCAT;
    for (int o = t; o < NPROJ; o += 256) {
      float v;
      if (o < 192)      v = bq[o];
      else if (o < 576) v = bkv[o-192];
      else if (o < 720) v = bqp[o-576];
      else              v = bkvp[o-720];
      bcat[o] = v;
    }
  }
}

// ---------------- Kernel A1: raw = sb @ WcatT^T via MFMA ----------------
__global__ __launch_bounds__(256) void k_proj_gemm(float* __restrict__ ws)
{
  const bf16h* sb    = (const bf16h*)(ws + OFF_SB);
  const bf16h* wcatT = (const bf16h*)(ws + OFF_WCT);
  float* raw = ws + OFF_RAW;
  const int t = threadIdx.x;
  const int wave = t >> 6, lane = t & 63;
  const int m0 = blockIdx.x*32 + (wave>>1)*16;
  const int n0 = blockIdx.y*32 + (wave&1)*16;
  const int lm = lane & 15, quad = lane >> 4;
  const bf16x8* pa = (const bf16x8*)(sb    + (size_t)(m0+lm)*CSD) + quad;
  const bf16x8* pb = (const bf16x8*)(wcatT + (size_t)(n0+lm)*CSD) + quad;
  f32x4 acc = {0.f, 0.f, 0.f, 0.f};
  #pragma unroll
  for (int kk = 0; kk < CSD/32; ++kk) {
    bf16x8 av = pa[kk*4];
    bf16x8 bv = pb[kk*4];
    acc = __builtin_amdgcn_mfma_f32_16x16x32_bf16(av, bv, acc, 0, 0, 0);
  }
  const int col = n0 + lm;
  #pragma unroll
  for (int r = 0; r < 4; ++r) {
    int row = m0 + quad*4 + r;
    raw[(size_t)row*NPROJ + col] = acc[r];
  }
}

// ---------------- Kernel A2: bias + scatter + point rotation (4 rows/block) ----------------
#define RPB 4
__global__ __launch_bounds__(256) void k_proj_epi(
    const float* __restrict__ rot, const float* __restrict__ trans,
    float* __restrict__ ws)
{
  __shared__ float praw[RPB][576];
  const int n0 = blockIdx.x*RPB, t = threadIdx.x;
  const float* raw = ws + OFF_RAW;
  const float* bcat = ws + OFF_BCAT;
  for (int idx = t; idx < RPB*NPROJ; idx += 256) {
    int r = idx / NPROJ, o = idx - r*NPROJ;
    int n = n0 + r;
    float v = raw[(size_t)n*NPROJ + o] + bcat[o];
    if (o < 192) {
      ws[OFF_Q + n*HC + o] = v;
    } else if (o < 576) {
      int col = o-192, h = col >> 5, rr = col & 31;
      if (rr < CHD) ws[OFF_K + n*HC + h*CHD + rr] = v;
      else          ws[OFF_V + n*HC + h*CHD + (rr-CHD)] = v;
    } else {
      praw[r][o-576] = v;
    }
  }
  __syncthreads();
  for (int m2 = t; m2 < RPB*192; m2 += 256) {
    int r = m2 / 192, m = m2 % 192;
    int n = n0 + r;
    float g0, g1, g2; float* dst;
    if (m < 48) {
      g0 = praw[r][m]; g1 = praw[r][48+m]; g2 = praw[r][96+m];
      int h = m >> 2, p = m & 3;
      dst = ws + OFF_QP + ((n*NH+h)*PQN + p)*3;
    } else {
      int mm = m - 48;
      g0 = praw[r][144+mm]; g1 = praw[r][288+mm]; g2 = praw[r][432+mm];
      int h = mm / 12, pp = mm % 12;
      if (pp < PQN) dst = ws + OFF_KP + ((n*NH+h)*PQN + pp)*3;
      else          dst = ws + OFF_VP + ((n*NH+h)*PVN + (pp-PQN))*3;
    }
    #pragma unroll
    for (int x = 0; x < 3; ++x)
      dst[x] = rot[n*9+x*3+0]*g0 + rot[n*9+x*3+1]*g1 + rot[n*9+x*3+2]*g2 + trans[n*3+x];
  }
}

// ---------------- Kernel B: fused b_pair + scores + softmax + o_pair, one block per i ----------------
__global__ __launch_bounds__(256) void k_fused(
    const float* __restrict__ z, const float* __restrict__ Wb, const float* __restrict__ bb,
    const float* __restrict__ mask, const float* __restrict__ head_w,
    float* __restrict__ ws)
{
  __shared__ float bp[NH][NN];       // 24576 B
  __shared__ float wl[CZD*NH];       // 6144 B
  __shared__ float qv_s[NH][CHD];    // 768 B
  __shared__ float qp_s[NH][12];     // 576 B
  __shared__ float hw_s[NH];         // 48 B
  const int i = blockIdx.x, t = threadIdx.x;

  // preamble: stride-256 loops (round-6 bug: branches assumed >=348 threads)
  for (int idx = t; idx < CZD*NH; idx += 256) wl[idx] = Wb[idx];
  for (int m = t; m < HC; m += 256) qv_s[m>>4][m&15] = ws[OFF_Q + i*HC + m];
  for (int m = t; m < NH*12; m += 256) qp_s[m/12][m%12] = ws[OFF_QP + i*NH*12 + m];
  if (t < NH) hw_s[t] = log1pf(expf(head_w[t])) * 0.13608276348795434f; // softplus*sqrt(1/54)
  __syncthreads();

  // ---- Phase A: bp[h][j] = z[i,j,:]@Wb + bb  (4 lanes/row, shfl-reduce) ----
  {
    const int qr = t & 3, pg = t >> 2;   // 4 lanes per row, 64 rows per pass
    for (int pass = 0; pass < 8; ++pass) {
      const int j = pass*64 + pg;
      const float4* zp = (const float4*)(z + ((size_t)i*NN + j)*CZD + qr*32);
      float acc[NH];
      #pragma unroll
      for (int h = 0; h < NH; ++h) acc[h] = 0.f;
      #pragma unroll
      for (int e = 0; e < 8; ++e) {
        float4 u = zp[e];
        float f[4] = { u.x, u.y, u.z, u.w };
        #pragma unroll
        for (int q2 = 0; q2 < 4; ++q2) {
          const float* w = wl + (qr*32 + e*4 + q2)*NH;
          #pragma unroll
          for (int h = 0; h < NH; ++h) acc[h] += f[q2]*w[h];
        }
      }
      #pragma unroll
      for (int h = 0; h < NH; ++h) {
        acc[h] += __shfl_xor(acc[h], 1);
        acc[h] += __shfl_xor(acc[h], 2);
      }
      #pragma unroll
      for (int e = 0; e < 3; ++e) {
        int h = qr*3 + e;
        bp[h][j] = acc[h] + bb[h];
      }
    }
  }
  __syncthreads();

  // ---- Phase B: scores in-place (wave hg owns heads hg*3..hg*3+2) ----
  const int jl = t & 63, hg = t >> 6;
  const float mi = mask[i];
  #pragma unroll
  for (int k = 0; k < 8; ++k) {
    const int j = jl + k*64;
    const float mj = mask[j];
    const float* kr = ws + OFF_K + j*HC;
    const float* kp = ws + OFF_KP + j*NH*12;
    #pragma unroll
    for (int e = 0; e < 3; ++e) {
      const int h = hg*3 + e;
      float dot = 0.f;
      #pragma unroll
      for (int c = 0; c < CHD; ++c) dot += qv_s[h][c]*kr[h*CHD + c];
      float d2 = 0.f;
      #pragma unroll
      for (int x = 0; x < 12; ++x) { float d = qp_s[h][x] - kp[h*12 + x]; d2 += d*d; }
      float v = dot*0.14433756729740643f + 0.57735026918962576f*bp[h][j]
              - 0.5f*hw_s[h]*d2 + 100000.0f*(mi*mj - 1.0f);
      bp[h][j] = v;
    }
  }
  // ---- Phase C: softmax (same-thread slots; shfl within wave) ----
  #pragma unroll
  for (int e = 0; e < 3; ++e) {
    const int h = hg*3 + e;
    float v[8];
    float m = -1e30f;
    #pragma unroll
    for (int k = 0; k < 8; ++k) { v[k] = bp[h][jl + k*64]; m = fmaxf(m, v[k]); }
    for (int off = 32; off > 0; off >>= 1) m = fmaxf(m, __shfl_xor(m, off));
    float sum = 0.f;
    #pragma unroll
    for (int k = 0; k < 8; ++k) { v[k] = expf(v[k]-m); sum += v[k]; }
    for (int off = 32; off > 0; off >>= 1) sum += __shfl_xor(sum, off);
    const float inv = 1.0f/sum;
    #pragma unroll
    for (int k = 0; k < 8; ++k) {
      float av = v[k]*inv;
      bp[h][jl + k*64] = av;
      ws[OFF_A + (size_t)h*NSQ + i*NN + jl + k*64] = av;
    }
  }
  __syncthreads();

  // ---- Phase D: o_pair (second z pass, L2/L3-resident) ----
  {
    const int cg = t & 63, hg2 = t >> 6;
    const int c0 = cg*2;
    float acc[3][2] = {{0.f,0.f},{0.f,0.f},{0.f,0.f}};
    #pragma unroll 4
    for (int jj = 0; jj < NN; ++jj) {
      float2 zz = *(const float2*)(z + ((size_t)i*NN + jj)*CZD + c0);
      #pragma unroll
      for (int e = 0; e < 3; ++e) {
        float av = bp[hg2*3+e][jj];
        acc[e][0] += av*zz.x;
        acc[e][1] += av*zz.y;
      }
    }
    bf16h* dst = (bf16h*)(ws + OFF_CATB) + (size_t)i*OUTD + 576;
    #pragma unroll
    for (int e = 0; e < 3; ++e) {
      int h = hg2*3+e;
      dst[h*CZD + c0]   = __float2bfloat16(acc[e][0]);
      dst[h*CZD + c0+1] = __float2bfloat16(acc[e][1]);
    }
  }
}

// ---------------- Kernel E: o + o_pt (+ inverse rotation + norm) -> catb (bf16) ----------------
__global__ __launch_bounds__(512) void k_oacc(
    const float* __restrict__ rot, const float* __restrict__ trans,
    float* __restrict__ ws)
{
  __shared__ float al[2][NH][66];
  __shared__ float optl[2][288];
  const int i0 = blockIdx.x*2, t = threadIdx.x;
  float acc[2] = {0.f, 0.f};
  int hsel = 0;
  const float* src = ws;
  int off = 0, stride = 0;
  if (t < 192)      { hsel = t >> 4;      src = ws + OFF_V;  off = t;     stride = HC;  }
  else if (t < 480) { hsel = (t-192)/24;  src = ws + OFF_VP; off = t-192; stride = 288; }
  for (int jb = 0; jb < NN; jb += 64) {
    __syncthreads();
    for (int idx = t; idx < 2*NH*64; idx += 512) {
      int ii = idx / 768;
      int rem = idx - ii*768;
      al[ii][rem>>6][rem&63] = ws[OFF_A + (size_t)(rem>>6)*NSQ + (i0+ii)*NN + jb + (rem&63)];
    }
    __syncthreads();
    if (t < 480) {
      #pragma unroll 4
      for (int jj = 0; jj < 64; ++jj) {
        float val = src[(size_t)(jb+jj)*stride + off];
        acc[0] += al[0][hsel][jj]*val;
        acc[1] += al[1][hsel][jj]*val;
      }
    }
  }
  bf16h* catb = (bf16h*)(ws + OFF_CATB);
  if (t < 192) {
    catb[(size_t)i0*OUTD + t]     = __float2bfloat16(acc[0]);
    catb[(size_t)(i0+1)*OUTD + t] = __float2bfloat16(acc[1]);
  } else if (t < 480) {
    optl[0][t-192] = acc[0];
    optl[1][t-192] = acc[1];
  }
  __syncthreads();
  if (t < 192) {
    int ii = t / 96, m = t - (t/96)*96;
    int h = m >> 3, p = m & 7;
    int n = i0 + ii;
    float g[3], Tl[3];
    #pragma unroll
    for (int y = 0; y < 3; ++y) { g[y] = optl[ii][h*24 + p*3 + y]; Tl[y] = trans[n*3+y]; }
    float nrm = 1e-8f;
    float loc[3];
    #pragma unroll
    for (int x = 0; x < 3; ++x) {
      float v = 0.f;
      #pragma unroll
      for (int y = 0; y < 3; ++y) v += rot[n*9 + y*3 + x] * (g[y]-Tl[y]);
      loc[x] = v; nrm += v*v;
    }
    nrm = sqrtf(nrm);
    bf16h* crow = catb + (size_t)n*OUTD;
    crow[192 + 0*96 + m] = __float2bfloat16(loc[0]);
    crow[192 + 1*96 + m] = __float2bfloat16(loc[1]);
    crow[192 + 2*96 + m] = __float2bfloat16(loc[2]);
    crow[480 + m]        = __float2bfloat16(nrm);
  }
}

// ---------------- Kernel F: out = catb @ WoutT^T + bout via MFMA ----------------
__global__ __launch_bounds__(256) void k_out_mfma(
    const float* __restrict__ bout, const float* __restrict__ ws_c, float* __restrict__ out)
{
  const bf16h* catb  = (const bf16h*)(ws_c + OFF_CATB);
  const bf16h* woutT = (const bf16h*)(ws_c + OFF_WOT);
  const int t = threadIdx.x;
  const int wave = t >> 6, lane = t & 63;
  const int m0 = blockIdx.x*32 + (wave>>1)*16;
  const int n0 = blockIdx.y*32 + (wave&1)*16;
  const int lm = lane & 15, quad = lane >> 4;
  const bf16x8* pa = (const bf16x8*)(catb  + (size_t)(m0+lm)*OUTD) + quad;
  const bf16x8* pb = (const bf16x8*)(woutT + (size_t)(n0+lm)*OUTD) + quad;
  f32x4 acc = {0.f, 0.f, 0.f, 0.f};
  #pragma unroll 4
  for (int kk = 0; kk < OUTD/32; ++kk) {
    bf16x8 av = pa[kk*4];
    bf16x8 bv = pb[kk*4];
    acc = __builtin_amdgcn_mfma_f32_16x16x32_bf16(av, bv, acc, 0, 0, 0);
  }
  const int col = n0 + lm;
  const float bb = bout[col];
  #pragma unroll
  for (int r = 0; r < 4; ++r) {
    int row = m0 + quad*4 + r;
    out[(size_t)row*CSD + col] = acc[r] + bb;
  }
}

extern "C" void kernel_launch(void* const* d_in, const int* in_sizes, int n_in,
                              void* d_out, int out_size, void* d_ws, size_t ws_size,
                              hipStream_t stream)
{
  const float* s     = (const float*)d_in[0];
  const float* z     = (const float*)d_in[1];
  const float* rot   = (const float*)d_in[2];
  const float* trans = (const float*)d_in[3];
  const float* mask  = (const float*)d_in[4];
  const float* Wq    = (const float*)d_in[5];
  const float* bq    = (const float*)d_in[6];
  const float* Wkv   = (const float*)d_in[7];
  const float* bkv   = (const float*)d_in[8];
  const float* Wqp   = (const float*)d_in[9];
  const float* bqp   = (const float*)d_in[10];
  const float* Wkvp  = (const float*)d_in[11];
  const float* bkvp  = (const float*)d_in[12];
  const float* Wb    = (const float*)d_in[13];
  const float* bb    = (const float*)d_in[14];
  const float* hwts  = (const float*)d_in[15];
  const float* Wout  = (const float*)d_in[16];
  const float* bout  = (const float*)d_in[17];
  float* ws  = (float*)d_ws;
  float* out = (float*)d_out;

  hipLaunchKernelGGL(k_wcat, dim3(NPROJ + 128 + CSD + 1), dim3(256), 0, stream,
                     s, Wq, bq, Wkv, bkv, Wqp, bqp, Wkvp, bkvp, Wout, ws);
  hipLaunchKernelGGL(k_proj_gemm, dim3(NN/32, NPROJ/32), dim3(256), 0, stream, ws);
  hipLaunchKernelGGL(k_proj_epi,  dim3(NN/RPB), dim3(256), 0, stream, rot, trans, ws);
  hipLaunchKernelGGL(k_fused, dim3(NN), dim3(256), 0, stream, z, Wb, bb, mask, hwts, ws);
  hipLaunchKernelGGL(k_oacc,  dim3(NN/2),    dim3(512), 0, stream, rot, trans, ws);
  hipLaunchKernelGGL(k_out_mfma, dim3(NN/32, CSD/32), dim3(256), 0, stream, bout, ws, out);
}

// Round 8
// 435.474 us; speedup vs baseline: 1.0301x; 1.0301x over previous
//
#include <hip/hip_runtime.h>
#include <hip/hip_bf16.h>

typedef __hip_bfloat16 bf16h;
typedef short bf16x8 __attribute__((ext_vector_type(8)));
typedef float f32x4 __attribute__((ext_vector_type(4)));

#define NH 12
#define CHD 16
#define PQN 4
#define PVN 8
#define CSD 384
#define CZD 128
#define NN 512
#define HC 192
#define OUTD 2112
#define NSQ (NN*NN)
#define NPROJ 1152

// ws layout (float offsets). a aliases proj scratch (stream-ordered, safe).
#define OFF_Q    0u
#define OFF_K    98304u
#define OFF_V    196608u
#define OFF_QP   294912u
#define OFF_KP   368640u
#define OFF_VP   442368u
#define OFF_A    589824u
#define OFF_RAW  589824u     /* f32 512x1152 = 589824 floats -> ends 1179648 */
#define OFF_SB   1179648u    /* bf16 512x384  = 98304 floats -> ends 1277952 */
#define OFF_WCT  1277952u    /* bf16 1152x384 = 221184 floats -> ends 1499136 (< 3735552 OK) */
#define OFF_CATB 3735552u    /* bf16 512x2112 = 540672 floats */
#define OFF_WOT  4276224u    /* bf16 384x2112 = 405504 floats */
#define OFF_BCAT 4681728u    /* f32 1152 -> end 4682880 floats = 18.73 MB */

// ---------------- Kernel W1: pack weights/s to bf16, concat biases ----------------
__global__ __launch_bounds__(256) void k_wcat(
    const float* __restrict__ s,
    const float* __restrict__ Wq, const float* __restrict__ bq,
    const float* __restrict__ Wkv, const float* __restrict__ bkv,
    const float* __restrict__ Wqp, const float* __restrict__ bqp,
    const float* __restrict__ Wkvp, const float* __restrict__ bkvp,
    const float* __restrict__ Wout, float* __restrict__ ws)
{
  const int b = blockIdx.x, t = threadIdx.x;
  if (b < NPROJ) {
    const float* W; int col, ld;
    if (b < 192)      { W = Wq;   col = b;     ld = 192; }
    else if (b < 576) { W = Wkv;  col = b-192; ld = 384; }
    else if (b < 720) { W = Wqp;  col = b-576; ld = 144; }
    else              { W = Wkvp; col = b-720; ld = 432; }
    bf16h* dst = (bf16h*)(ws + OFF_WCT) + (size_t)b*CSD;
    for (int c = t; c < CSD; c += 256) dst[c] = __float2bfloat16(W[c*ld + col]);
  } else if (b < NPROJ + 128) {
    const int n0 = (b - NPROJ)*4;
    bf16h* sb = (bf16h*)(ws + OFF_SB);
    for (int idx = t; idx < 4*CSD; idx += 256)
      sb[(size_t)n0*CSD + idx] = __float2bfloat16(s[(size_t)n0*CSD + idx]);
  } else if (b < NPROJ + 128 + CSD) {
    const int n = b - (NPROJ + 128);
    bf16h* woutT = (bf16h*)(ws + OFF_WOT);
    for (int k = t; k < OUTD; k += 256)
      woutT[(size_t)n*OUTD + k] = __float2bfloat16(Wout[(size_t)k*CSD + n]);
  } else {
    float* bcat = ws + OFF_BCAT;
    for (int o = t; o < NPROJ; o += 256) {
      float v;
      if (o < 192)      v = bq[o];
      else if (o < 576) v = bkv[o-192];
      else if (o < 720) v = bqp[o-576];
      else              v = bkvp[o-720];
      bcat[o] = v;
    }
  }
}

// ---------------- Kernel A1: raw = sb @ WcatT^T via MFMA ----------------
__global__ __launch_bounds__(256) void k_proj_gemm(float* __restrict__ ws)
{
  const bf16h* sb    = (const bf16h*)(ws + OFF_SB);
  const bf16h* wcatT = (const bf16h*)(ws + OFF_WCT);
  float* raw = ws + OFF_RAW;
  const int t = threadIdx.x;
  const int wave = t >> 6, lane = t & 63;
  const int m0 = blockIdx.x*32 + (wave>>1)*16;
  const int n0 = blockIdx.y*32 + (wave&1)*16;
  const int lm = lane & 15, quad = lane >> 4;
  const bf16x8* pa = (const bf16x8*)(sb    + (size_t)(m0+lm)*CSD) + quad;
  const bf16x8* pb = (const bf16x8*)(wcatT + (size_t)(n0+lm)*CSD) + quad;
  f32x4 acc = {0.f, 0.f, 0.f, 0.f};
  #pragma unroll
  for (int kk = 0; kk < CSD/32; ++kk) {
    bf16x8 av = pa[kk*4];
    bf16x8 bv = pb[kk*4];
    acc = __builtin_amdgcn_mfma_f32_16x16x32_bf16(av, bv, acc, 0, 0, 0);
  }
  const int col = n0 + lm;
  #pragma unroll
  for (int r = 0; r < 4; ++r) {
    int row = m0 + quad*4 + r;
    raw[(size_t)row*NPROJ + col] = acc[r];
  }
}

// ---------------- Kernel A2: bias + scatter + point rotation (4 rows/block) ----------------
#define RPB 4
__global__ __launch_bounds__(256) void k_proj_epi(
    const float* __restrict__ rot, const float* __restrict__ trans,
    float* __restrict__ ws)
{
  __shared__ float praw[RPB][576];
  const int n0 = blockIdx.x*RPB, t = threadIdx.x;
  const float* raw = ws + OFF_RAW;
  const float* bcat = ws + OFF_BCAT;
  for (int idx = t; idx < RPB*NPROJ; idx += 256) {
    int r = idx / NPROJ, o = idx - r*NPROJ;
    int n = n0 + r;
    float v = raw[(size_t)n*NPROJ + o] + bcat[o];
    if (o < 192) {
      ws[OFF_Q + n*HC + o] = v;
    } else if (o < 576) {
      int col = o-192, h = col >> 5, rr = col & 31;
      if (rr < CHD) ws[OFF_K + n*HC + h*CHD + rr] = v;
      else          ws[OFF_V + n*HC + h*CHD + (rr-CHD)] = v;
    } else {
      praw[r][o-576] = v;
    }
  }
  __syncthreads();
  for (int m2 = t; m2 < RPB*192; m2 += 256) {
    int r = m2 / 192, m = m2 % 192;
    int n = n0 + r;
    float g0, g1, g2; float* dst;
    if (m < 48) {
      g0 = praw[r][m]; g1 = praw[r][48+m]; g2 = praw[r][96+m];
      int h = m >> 2, p = m & 3;
      dst = ws + OFF_QP + ((n*NH+h)*PQN + p)*3;
    } else {
      int mm = m - 48;
      g0 = praw[r][144+mm]; g1 = praw[r][288+mm]; g2 = praw[r][432+mm];
      int h = mm / 12, pp = mm % 12;
      if (pp < PQN) dst = ws + OFF_KP + ((n*NH+h)*PQN + pp)*3;
      else          dst = ws + OFF_VP + ((n*NH+h)*PVN + (pp-PQN))*3;
    }
    #pragma unroll
    for (int x = 0; x < 3; ++x)
      dst[x] = rot[n*9+x*3+0]*g0 + rot[n*9+x*3+1]*g1 + rot[n*9+x*3+2]*g2 + trans[n*3+x];
  }
}

// ---------------- Kernel B: b_pair, coalesced via LDS z-tile ----------------
// grid (NN/64, NN): block = (j-tile of 64 rows, i). Stage 64x128 z-tile into
// LDS (coalesced float4), one thread per (row, 3 heads) from LDS.
__global__ __launch_bounds__(256) void k_bpair(
    const float* __restrict__ z, const float* __restrict__ Wb, const float* __restrict__ bb,
    float* __restrict__ ws)
{
  __shared__ float zt[64][130];      // pad 130: bank (2*row+c)%32 -> 2-way (free)
  __shared__ float wl[CZD*NH];
  const int i = blockIdx.y, jb = blockIdx.x*64;
  const int t = threadIdx.x;
  for (int idx = t; idx < CZD*NH; idx += 256) wl[idx] = Wb[idx];
  const float4* zbase = (const float4*)(z + ((size_t)i*NN + jb)*CZD);
  for (int idx = t; idx < 64*(CZD/4); idx += 256) {
    float4 u = zbase[idx];
    int row = idx >> 5, c4 = (idx & 31)*4;
    zt[row][c4]   = u.x;
    zt[row][c4+1] = u.y;
    zt[row][c4+2] = u.z;
    zt[row][c4+3] = u.w;
  }
  __syncthreads();
  const int lane = t & 63, w = t >> 6;
  const int h0 = w*3;
  float acc0 = bb[h0], acc1 = bb[h0+1], acc2 = bb[h0+2];
  #pragma unroll 8
  for (int c = 0; c < CZD; ++c) {
    float zv = zt[lane][c];
    const float* wp = wl + c*NH + h0;   // wave-uniform -> LDS broadcast
    acc0 += zv*wp[0];
    acc1 += zv*wp[1];
    acc2 += zv*wp[2];
  }
  const float sc13 = 0.57735026918962576f;   // sqrt(1/3)
  size_t base = OFF_A + (size_t)h0*NSQ + (size_t)i*NN + jb + lane;
  ws[base]         = acc0*sc13;
  ws[base + NSQ]   = acc1*sc13;
  ws[base + 2*NSQ] = acc2*sc13;
}

// ---------------- Kernel C: scores + softmax; 4 (i,h)-waves per block ----------------
__global__ __launch_bounds__(256) void k_attn(
    const float* __restrict__ mask, const float* __restrict__ head_w,
    float* __restrict__ ws)
{
  const int i = blockIdx.x, t = threadIdx.x;
  const int h = blockIdx.y*4 + (t >> 6);
  const int lane = t & 63;
  const float* q = ws + OFF_Q + i*HC + h*CHD;
  float qv[CHD];
  #pragma unroll
  for (int c = 0; c < CHD; ++c) qv[c] = q[c];
  float qp[12];
  const float* qpp = ws + OFF_QP + (i*NH+h)*PQN*3;
  #pragma unroll
  for (int e = 0; e < 12; ++e) qp[e] = qpp[e];
  const float hw = log1pf(expf(head_w[h])) * 0.13608276348795434f; // softplus * sqrt(1/54)
  const float mi = mask[i];
  float sc[8];
  #pragma unroll
  for (int jj = 0; jj < 8; ++jj) {
    const int j = lane + jj*64;
    const float* kr = ws + OFF_K + j*HC + h*CHD;
    float dot = 0.f;
    #pragma unroll
    for (int c = 0; c < CHD; ++c) dot += qv[c]*kr[c];
    const float* kp = ws + OFF_KP + (j*NH+h)*PQN*3;
    float d2 = 0.f;
    #pragma unroll
    for (int e = 0; e < 12; ++e) { float d = qp[e]-kp[e]; d2 += d*d; }
    float b = ws[OFF_A + (size_t)h*NSQ + i*NN + j];   // pre-scaled b_pair
    sc[jj] = dot*0.14433756729740643f + b - 0.5f*hw*d2
           + 100000.0f*(mi*mask[j] - 1.0f);
  }
  float m = sc[0];
  #pragma unroll
  for (int jj = 1; jj < 8; ++jj) m = fmaxf(m, sc[jj]);
  for (int off = 32; off > 0; off >>= 1) m = fmaxf(m, __shfl_xor(m, off));
  float ssum = 0.f;
  #pragma unroll
  for (int jj = 0; jj < 8; ++jj) { sc[jj] = expf(sc[jj]-m); ssum += sc[jj]; }
  for (int off = 32; off > 0; off >>= 1) ssum += __shfl_xor(ssum, off);
  const float inv = 1.0f/ssum;
  #pragma unroll
  for (int jj = 0; jj < 8; ++jj)
    ws[OFF_A + (size_t)h*NSQ + i*NN + lane + jj*64] = sc[jj]*inv;
}

// ---------------- Kernel D: o_pair[i,h,c] = sum_j a[h,i,j]*z[i,j,c] -> catb (bf16) ----------------
__global__ __launch_bounds__(256) void k_opair(
    const float* __restrict__ z, float* __restrict__ ws)
{
  __shared__ float al[NH][66];               // padded h-stride
  const int i = blockIdx.x, t = threadIdx.x;
  const int cg = t & 63, hg = t >> 6;        // c0 = 2*cg, heads hg*3..hg*3+2
  const int c0 = cg*2;
  float acc[3][2] = {{0.f,0.f},{0.f,0.f},{0.f,0.f}};
  for (int jb = 0; jb < NN; jb += 64) {
    __syncthreads();
    #pragma unroll
    for (int r = 0; r < 3; ++r) {
      int idx = t + r*256;                   // 768 = 12*64 values
      al[idx>>6][idx&63] = ws[OFF_A + (size_t)(idx>>6)*NSQ + i*NN + jb + (idx&63)];
    }
    __syncthreads();
    #pragma unroll 4
    for (int jj = 0; jj < 64; ++jj) {
      float2 zz = *(const float2*)(z + ((size_t)i*NN + jb + jj)*CZD + c0);
      #pragma unroll
      for (int e = 0; e < 3; ++e) {
        float av = al[hg*3+e][jj];
        acc[e][0] += av*zz.x;
        acc[e][1] += av*zz.y;
      }
    }
  }
  bf16h* dst = (bf16h*)(ws + OFF_CATB) + (size_t)i*OUTD + 576;
  #pragma unroll
  for (int e = 0; e < 3; ++e) {
    int h = hg*3+e;
    dst[h*CZD + c0]   = __float2bfloat16(acc[e][0]);
    dst[h*CZD + c0+1] = __float2bfloat16(acc[e][1]);
  }
}

// ---------------- Kernel E: o + o_pt (+ inverse rotation + norm) -> catb (bf16) ----------------
__global__ __launch_bounds__(512) void k_oacc(
    const float* __restrict__ rot, const float* __restrict__ trans,
    float* __restrict__ ws)
{
  __shared__ float al[2][NH][66];
  __shared__ float optl[2][288];
  const int i0 = blockIdx.x*2, t = threadIdx.x;
  float acc[2] = {0.f, 0.f};
  int hsel = 0;
  const float* src = ws;
  int off = 0, stride = 0;
  if (t < 192)      { hsel = t >> 4;      src = ws + OFF_V;  off = t;     stride = HC;  }
  else if (t < 480) { hsel = (t-192)/24;  src = ws + OFF_VP; off = t-192; stride = 288; }
  for (int jb = 0; jb < NN; jb += 64) {
    __syncthreads();
    for (int idx = t; idx < 2*NH*64; idx += 512) {
      int ii = idx / 768;
      int rem = idx - ii*768;
      al[ii][rem>>6][rem&63] = ws[OFF_A + (size_t)(rem>>6)*NSQ + (i0+ii)*NN + jb + (rem&63)];
    }
    __syncthreads();
    if (t < 480) {
      #pragma unroll 4
      for (int jj = 0; jj < 64; ++jj) {
        float val = src[(size_t)(jb+jj)*stride + off];
        acc[0] += al[0][hsel][jj]*val;
        acc[1] += al[1][hsel][jj]*val;
      }
    }
  }
  bf16h* catb = (bf16h*)(ws + OFF_CATB);
  if (t < 192) {
    catb[(size_t)i0*OUTD + t]     = __float2bfloat16(acc[0]);
    catb[(size_t)(i0+1)*OUTD + t] = __float2bfloat16(acc[1]);
  } else if (t < 480) {
    optl[0][t-192] = acc[0];
    optl[1][t-192] = acc[1];
  }
  __syncthreads();
  if (t < 192) {
    int ii = t / 96, m = t - (t/96)*96;
    int h = m >> 3, p = m & 7;
    int n = i0 + ii;
    float g[3], Tl[3];
    #pragma unroll
    for (int y = 0; y < 3; ++y) { g[y] = optl[ii][h*24 + p*3 + y]; Tl[y] = trans[n*3+y]; }
    float nrm = 1e-8f;
    float loc[3];
    #pragma unroll
    for (int x = 0; x < 3; ++x) {
      float v = 0.f;
      #pragma unroll
      for (int y = 0; y < 3; ++y) v += rot[n*9 + y*3 + x] * (g[y]-Tl[y]);
      loc[x] = v; nrm += v*v;
    }
    nrm = sqrtf(nrm);
    bf16h* crow = catb + (size_t)n*OUTD;
    crow[192 + 0*96 + m] = __float2bfloat16(loc[0]);
    crow[192 + 1*96 + m] = __float2bfloat16(loc[1]);
    crow[192 + 2*96 + m] = __float2bfloat16(loc[2]);
    crow[480 + m]        = __float2bfloat16(nrm);
  }
}

// ---------------- Kernel F: out = catb @ WoutT^T + bout via MFMA ----------------
__global__ __launch_bounds__(256) void k_out_mfma(
    const float* __restrict__ bout, const float* __restrict__ ws_c, float* __restrict__ out)
{
  const bf16h* catb  = (const bf16h*)(ws_c + OFF_CATB);
  const bf16h* woutT = (const bf16h*)(ws_c + OFF_WOT);
  const int t = threadIdx.x;
  const int wave = t >> 6, lane = t & 63;
  const int m0 = blockIdx.x*32 + (wave>>1)*16;
  const int n0 = blockIdx.y*32 + (wave&1)*16;
  const int lm = lane & 15, quad = lane >> 4;
  const bf16x8* pa = (const bf16x8*)(catb  + (size_t)(m0+lm)*OUTD) + quad;
  const bf16x8* pb = (const bf16x8*)(woutT + (size_t)(n0+lm)*OUTD) + quad;
  f32x4 acc = {0.f, 0.f, 0.f, 0.f};
  #pragma unroll 4
  for (int kk = 0; kk < OUTD/32; ++kk) {
    bf16x8 av = pa[kk*4];
    bf16x8 bv = pb[kk*4];
    acc = __builtin_amdgcn_mfma_f32_16x16x32_bf16(av, bv, acc, 0, 0, 0);
  }
  const int col = n0 + lm;
  const float bb = bout[col];
  #pragma unroll
  for (int r = 0; r < 4; ++r) {
    int row = m0 + quad*4 + r;
    out[(size_t)row*CSD + col] = acc[r] + bb;
  }
}

extern "C" void kernel_launch(void* const* d_in, const int* in_sizes, int n_in,
                              void* d_out, int out_size, void* d_ws, size_t ws_size,
                              hipStream_t stream)
{
  const float* s     = (const float*)d_in[0];
  const float* z     = (const float*)d_in[1];
  const float* rot   = (const float*)d_in[2];
  const float* trans = (const float*)d_in[3];
  const float* mask  = (const float*)d_in[4];
  const float* Wq    = (const float*)d_in[5];
  const float* bq    = (const float*)d_in[6];
  const float* Wkv   = (const float*)d_in[7];
  const float* bkv   = (const float*)d_in[8];
  const float* Wqp   = (const float*)d_in[9];
  const float* bqp   = (const float*)d_in[10];
  const float* Wkvp  = (const float*)d_in[11];
  const float* bkvp  = (const float*)d_in[12];
  const float* Wb    = (const float*)d_in[13];
  const float* bb    = (const float*)d_in[14];
  const float* hwts  = (const float*)d_in[15];
  const float* Wout  = (const float*)d_in[16];
  const float* bout  = (const float*)d_in[17];
  float* ws  = (float*)d_ws;
  float* out = (float*)d_out;

  hipLaunchKernelGGL(k_wcat, dim3(NPROJ + 128 + CSD + 1), dim3(256), 0, stream,
                     s, Wq, bq, Wkv, bkv, Wqp, bqp, Wkvp, bkvp, Wout, ws);
  hipLaunchKernelGGL(k_proj_gemm, dim3(NN/32, NPROJ/32), dim3(256), 0, stream, ws);
  hipLaunchKernelGGL(k_proj_epi,  dim3(NN/RPB), dim3(256), 0, stream, rot, trans, ws);
  hipLaunchKernelGGL(k_bpair, dim3(NN/64, NN), dim3(256), 0, stream, z, Wb, bb, ws);
  hipLaunchKernelGGL(k_attn,  dim3(NN, 3),     dim3(256), 0, stream, mask, hwts, ws);
  hipLaunchKernelGGL(k_opair, dim3(NN),        dim3(256), 0, stream, z, ws);
  hipLaunchKernelGGL(k_oacc,  dim3(NN/2),      dim3(512), 0, stream, rot, trans, ws);
  hipLaunchKernelGGL(k_out_mfma, dim3(NN/32, CSD/32), dim3(256), 0, stream, bout, ws, out);
}

// Round 9
// 431.333 us; speedup vs baseline: 1.0400x; 1.0096x over previous
//
#include <hip/hip_runtime.h>
#include <hip/hip_bf16.h>

typedef __hip_bfloat16 bf16h;
typedef short bf16x8 __attribute__((ext_vector_type(8)));
typedef float f32x4 __attribute__((ext_vector_type(4)));

#define NH 12
#define CHD 16
#define PQN 4
#define PVN 8
#define CSD 384
#define CZD 128
#define NN 512
#define HC 192
#define OUTD 2112
#define NSQ (NN*NN)
#define NPROJ 1152

// ws layout (float offsets). a aliases proj scratch (stream-ordered, safe).
// K is HEAD-MAJOR [h][n][16]; KP is HEAD-MAJOR [h][n][4][3]. Q/V/QP/VP row-major.
#define OFF_Q    0u
#define OFF_K    98304u
#define OFF_V    196608u
#define OFF_QP   294912u
#define OFF_KP   368640u
#define OFF_VP   442368u
#define OFF_A    589824u
#define OFF_RAW  589824u     /* f32 512x1152 = 589824 floats -> ends 1179648 */
#define OFF_SB   1179648u    /* bf16 512x384  = 98304 floats -> ends 1277952 */
#define OFF_WCT  1277952u    /* bf16 1152x384 = 221184 floats -> ends 1499136 (< 3735552 OK) */
#define OFF_CATB 3735552u    /* bf16 512x2112 = 540672 floats */
#define OFF_WOT  4276224u    /* bf16 384x2112 = 405504 floats */
#define OFF_BCAT 4681728u    /* f32 1152 -> end 4682880 floats = 18.73 MB */

// ---------------- Kernel W1: pack weights/s to bf16, concat biases ----------------
__global__ __launch_bounds__(256) void k_wcat(
    const float* __restrict__ s,
    const float* __restrict__ Wq, const float* __restrict__ bq,
    const float* __restrict__ Wkv, const float* __restrict__ bkv,
    const float* __restrict__ Wqp, const float* __restrict__ bqp,
    const float* __restrict__ Wkvp, const float* __restrict__ bkvp,
    float* __restrict__ ws)
{
  const int b = blockIdx.x, t = threadIdx.x;
  if (b < NPROJ) {
    const float* W; int col, ld;
    if (b < 192)      { W = Wq;   col = b;     ld = 192; }
    else if (b < 576) { W = Wkv;  col = b-192; ld = 384; }
    else if (b < 720) { W = Wqp;  col = b-576; ld = 144; }
    else              { W = Wkvp; col = b-720; ld = 432; }
    bf16h* dst = (bf16h*)(ws + OFF_WCT) + (size_t)b*CSD;
    for (int c = t; c < CSD; c += 256) dst[c] = __float2bfloat16(W[c*ld + col]);
  } else if (b < NPROJ + 128) {
    const int n0 = (b - NPROJ)*4;
    bf16h* sb = (bf16h*)(ws + OFF_SB);
    for (int idx = t; idx < 4*CSD; idx += 256)
      sb[(size_t)n0*CSD + idx] = __float2bfloat16(s[(size_t)n0*CSD + idx]);
  } else {
    float* bcat = ws + OFF_BCAT;
    for (int o = t; o < NPROJ; o += 256) {
      float v;
      if (o < 192)      v = bq[o];
      else if (o < 576) v = bkv[o-192];
      else if (o < 720) v = bqp[o-576];
      else              v = bkvp[o-720];
      bcat[o] = v;
    }
  }
}

// ---------------- Kernel W2: WoutT[n][k] = bf16(Wout[k][n]) via 32x32 LDS tile ----------------
__global__ __launch_bounds__(256) void k_wtrans(
    const float* __restrict__ Wout, float* __restrict__ ws)
{
  __shared__ float til[32][33];
  const int n0 = blockIdx.x*32, k0 = blockIdx.y*32, t = threadIdx.x;
  for (int idx = t; idx < 1024; idx += 256) {
    int r = idx >> 5, c = idx & 31;
    til[r][c] = Wout[(size_t)(k0+r)*CSD + n0 + c];
  }
  __syncthreads();
  bf16h* woutT = (bf16h*)(ws + OFF_WOT);
  for (int idx = t; idx < 1024; idx += 256) {
    int r = idx >> 5, c = idx & 31;
    woutT[(size_t)(n0+r)*OUTD + k0 + c] = __float2bfloat16(til[c][r]);
  }
}

// ---------------- Kernel A1: raw = sb @ WcatT^T via MFMA ----------------
__global__ __launch_bounds__(256) void k_proj_gemm(float* __restrict__ ws)
{
  const bf16h* sb    = (const bf16h*)(ws + OFF_SB);
  const bf16h* wcatT = (const bf16h*)(ws + OFF_WCT);
  float* raw = ws + OFF_RAW;
  const int t = threadIdx.x;
  const int wave = t >> 6, lane = t & 63;
  const int m0 = blockIdx.x*32 + (wave>>1)*16;
  const int n0 = blockIdx.y*32 + (wave&1)*16;
  const int lm = lane & 15, quad = lane >> 4;
  const bf16x8* pa = (const bf16x8*)(sb    + (size_t)(m0+lm)*CSD) + quad;
  const bf16x8* pb = (const bf16x8*)(wcatT + (size_t)(n0+lm)*CSD) + quad;
  f32x4 acc = {0.f, 0.f, 0.f, 0.f};
  #pragma unroll
  for (int kk = 0; kk < CSD/32; ++kk) {
    bf16x8 av = pa[kk*4];
    bf16x8 bv = pb[kk*4];
    acc = __builtin_amdgcn_mfma_f32_16x16x32_bf16(av, bv, acc, 0, 0, 0);
  }
  const int col = n0 + lm;
  #pragma unroll
  for (int r = 0; r < 4; ++r) {
    int row = m0 + quad*4 + r;
    raw[(size_t)row*NPROJ + col] = acc[r];
  }
}

// ---------------- Kernel A2: bias + scatter + point rotation (4 rows/block) ----------------
#define RPB 4
__global__ __launch_bounds__(256) void k_proj_epi(
    const float* __restrict__ rot, const float* __restrict__ trans,
    float* __restrict__ ws)
{
  __shared__ float praw[RPB][576];
  const int n0 = blockIdx.x*RPB, t = threadIdx.x;
  const float* raw = ws + OFF_RAW;
  const float* bcat = ws + OFF_BCAT;
  for (int idx = t; idx < RPB*NPROJ; idx += 256) {
    int r = idx / NPROJ, o = idx - r*NPROJ;
    int n = n0 + r;
    float v = raw[(size_t)n*NPROJ + o] + bcat[o];
    if (o < 192) {
      ws[OFF_Q + n*HC + o] = v;
    } else if (o < 576) {
      int col = o-192, h = col >> 5, rr = col & 31;
      if (rr < CHD) ws[OFF_K + ((size_t)h*NN + n)*CHD + rr] = v;     // head-major K
      else          ws[OFF_V + n*HC + h*CHD + (rr-CHD)] = v;
    } else {
      praw[r][o-576] = v;
    }
  }
  __syncthreads();
  for (int m2 = t; m2 < RPB*192; m2 += 256) {
    int r = m2 / 192, m = m2 % 192;
    int n = n0 + r;
    float g0, g1, g2; float* dst;
    if (m < 48) {
      g0 = praw[r][m]; g1 = praw[r][48+m]; g2 = praw[r][96+m];
      int h = m >> 2, p = m & 3;
      dst = ws + OFF_QP + ((n*NH+h)*PQN + p)*3;
    } else {
      int mm = m - 48;
      g0 = praw[r][144+mm]; g1 = praw[r][288+mm]; g2 = praw[r][432+mm];
      int h = mm / 12, pp = mm % 12;
      if (pp < PQN) dst = ws + OFF_KP + (((size_t)h*NN + n)*PQN + pp)*3;  // head-major KP
      else          dst = ws + OFF_VP + ((n*NH+h)*PVN + (pp-PQN))*3;
    }
    #pragma unroll
    for (int x = 0; x < 3; ++x)
      dst[x] = rot[n*9+x*3+0]*g0 + rot[n*9+x*3+1]*g1 + rot[n*9+x*3+2]*g2 + trans[n*3+x];
  }
}

// ---------------- Kernel B: b_pair, coalesced via LDS z-tile ----------------
__global__ __launch_bounds__(256) void k_bpair(
    const float* __restrict__ z, const float* __restrict__ Wb, const float* __restrict__ bb,
    float* __restrict__ ws)
{
  __shared__ float zt[64][130];      // pad 130: 2-way bank aliasing (free)
  __shared__ float wl[CZD*NH];
  const int i = blockIdx.y, jb = blockIdx.x*64;
  const int t = threadIdx.x;
  for (int idx = t; idx < CZD*NH; idx += 256) wl[idx] = Wb[idx];
  const float4* zbase = (const float4*)(z + ((size_t)i*NN + jb)*CZD);
  for (int idx = t; idx < 64*(CZD/4); idx += 256) {
    float4 u = zbase[idx];
    int row = idx >> 5, c4 = (idx & 31)*4;
    zt[row][c4]   = u.x;
    zt[row][c4+1] = u.y;
    zt[row][c4+2] = u.z;
    zt[row][c4+3] = u.w;
  }
  __syncthreads();
  const int lane = t & 63, w = t >> 6;
  const int h0 = w*3;
  float acc0 = bb[h0], acc1 = bb[h0+1], acc2 = bb[h0+2];
  #pragma unroll 8
  for (int c = 0; c < CZD; ++c) {
    float zv = zt[lane][c];
    const float* wp = wl + c*NH + h0;   // wave-uniform -> LDS broadcast
    acc0 += zv*wp[0];
    acc1 += zv*wp[1];
    acc2 += zv*wp[2];
  }
  const float sc13 = 0.57735026918962576f;   // sqrt(1/3)
  size_t base = OFF_A + (size_t)h0*NSQ + (size_t)i*NN + jb + lane;
  ws[base]         = acc0*sc13;
  ws[base + NSQ]   = acc1*sc13;
  ws[base + 2*NSQ] = acc2*sc13;
}

// ---------------- Kernel C: scores + softmax; 4 (i,h)-waves per block; head-major K/KP ----------------
__global__ __launch_bounds__(256) void k_attn(
    const float* __restrict__ mask, const float* __restrict__ head_w,
    float* __restrict__ ws)
{
  const int i = blockIdx.x, t = threadIdx.x;
  const int h = blockIdx.y*4 + (t >> 6);
  const int lane = t & 63;
  const float* q = ws + OFF_Q + i*HC + h*CHD;
  float qv[CHD];
  #pragma unroll
  for (int c = 0; c < CHD; ++c) qv[c] = q[c];
  float qp[12];
  const float* qpp = ws + OFF_QP + (i*NH+h)*PQN*3;
  #pragma unroll
  for (int e = 0; e < 12; ++e) qp[e] = qpp[e];
  const float hw = log1pf(expf(head_w[h])) * 0.13608276348795434f; // softplus * sqrt(1/54)
  const float mi = mask[i];
  float sc[8];
  #pragma unroll
  for (int jj = 0; jj < 8; ++jj) {
    const int j = lane + jj*64;
    const float* kr = ws + OFF_K + ((size_t)h*NN + j)*CHD;    // contiguous stream
    float dot = 0.f;
    #pragma unroll
    for (int c = 0; c < CHD; ++c) dot += qv[c]*kr[c];
    const float* kp = ws + OFF_KP + ((size_t)h*NN + j)*12;    // contiguous stream
    float d2 = 0.f;
    #pragma unroll
    for (int e = 0; e < 12; ++e) { float d = qp[e]-kp[e]; d2 += d*d; }
    float b = ws[OFF_A + (size_t)h*NSQ + i*NN + j];   // pre-scaled b_pair
    sc[jj] = dot*0.14433756729740643f + b - 0.5f*hw*d2
           + 100000.0f*(mi*mask[j] - 1.0f);
  }
  float m = sc[0];
  #pragma unroll
  for (int jj = 1; jj < 8; ++jj) m = fmaxf(m, sc[jj]);
  for (int off = 32; off > 0; off >>= 1) m = fmaxf(m, __shfl_xor(m, off));
  float ssum = 0.f;
  #pragma unroll
  for (int jj = 0; jj < 8; ++jj) { sc[jj] = expf(sc[jj]-m); ssum += sc[jj]; }
  for (int off = 32; off > 0; off >>= 1) ssum += __shfl_xor(ssum, off);
  const float inv = 1.0f/ssum;
  #pragma unroll
  for (int jj = 0; jj < 8; ++jj)
    ws[OFF_A + (size_t)h*NSQ + i*NN + lane + jj*64] = sc[jj]*inv;
}

// ---------------- Kernel D: o_pair; grid (4, NN): 3 heads/block, wave-per-j-quarter ----------------
__global__ __launch_bounds__(256) void k_opair(
    const float* __restrict__ z, float* __restrict__ ws)
{
  __shared__ float al[3][NN];        // a for 3 heads (broadcast reads, no pad needed)
  __shared__ float ps[4][3][128];    // per-wave partials
  const int h3 = blockIdx.x, i = blockIdx.y, t = threadIdx.x;
  const int lane = t & 63, wv = t >> 6;
  for (int idx = t; idx < 3*NN; idx += 256)
    al[idx>>9][idx&511] = ws[OFF_A + (size_t)(h3*3 + (idx>>9))*NSQ + (size_t)i*NN + (idx&511)];
  __syncthreads();
  const int c0 = lane*2;
  float acc[3][2] = {{0.f,0.f},{0.f,0.f},{0.f,0.f}};
  const int j0 = wv*128;
  #pragma unroll 4
  for (int jj = 0; jj < 128; ++jj) {
    const int j = j0 + jj;
    float2 zz = *(const float2*)(z + ((size_t)i*NN + j)*CZD + c0);
    #pragma unroll
    for (int e = 0; e < 3; ++e) {
      float av = al[e][j];
      acc[e][0] += av*zz.x;
      acc[e][1] += av*zz.y;
    }
  }
  #pragma unroll
  for (int e = 0; e < 3; ++e) {
    ps[wv][e][c0]   = acc[e][0];
    ps[wv][e][c0+1] = acc[e][1];
  }
  __syncthreads();
  if (t < 192) {
    const int e = t >> 6, cl = (t & 63)*2;
    float s0 = ps[0][e][cl]   + ps[1][e][cl]   + ps[2][e][cl]   + ps[3][e][cl];
    float s1 = ps[0][e][cl+1] + ps[1][e][cl+1] + ps[2][e][cl+1] + ps[3][e][cl+1];
    bf16h* dst = (bf16h*)(ws + OFF_CATB) + (size_t)i*OUTD + 576 + (size_t)(h3*3+e)*CZD;
    dst[cl]   = __float2bfloat16(s0);
    dst[cl+1] = __float2bfloat16(s1);
  }
}

// ---------------- Kernel E: o + o_pt; one i per block (512 blocks) ----------------
__global__ __launch_bounds__(512) void k_oacc(
    const float* __restrict__ rot, const float* __restrict__ trans,
    float* __restrict__ ws)
{
  __shared__ float al[NH][516];      // pad 516: bank = (4*h + jj)%32, <=2-way (free)
  __shared__ float optl[288];
  const int i = blockIdx.x, t = threadIdx.x;
  for (int idx = t; idx < NH*NN; idx += 512)
    al[idx>>9][idx&511] = ws[OFF_A + (size_t)(idx>>9)*NSQ + (size_t)i*NN + (idx&511)];
  __syncthreads();
  float acc = 0.f;
  if (t < 192) {
    const float* src = ws + OFF_V + t;
    const int hsel = t >> 4;
    #pragma unroll 4
    for (int jj = 0; jj < NN; ++jj) acc += al[hsel][jj]*src[(size_t)jj*HC];
  } else if (t < 480) {
    const float* src = ws + OFF_VP + (t-192);
    const int hsel = (t-192)/24;
    #pragma unroll 4
    for (int jj = 0; jj < NN; ++jj) acc += al[hsel][jj]*src[(size_t)jj*288];
  }
  bf16h* catb = (bf16h*)(ws + OFF_CATB);
  if (t < 192)      catb[(size_t)i*OUTD + t] = __float2bfloat16(acc);
  else if (t < 480) optl[t-192] = acc;
  __syncthreads();
  if (t < 96) {
    const int h = t >> 3, p = t & 7;
    float g[3], Tl[3];
    #pragma unroll
    for (int y = 0; y < 3; ++y) { g[y] = optl[h*24 + p*3 + y]; Tl[y] = trans[i*3+y]; }
    float nrm = 1e-8f;
    float loc[3];
    #pragma unroll
    for (int x = 0; x < 3; ++x) {
      float v = 0.f;
      #pragma unroll
      for (int y = 0; y < 3; ++y) v += rot[i*9 + y*3 + x] * (g[y]-Tl[y]);
      loc[x] = v; nrm += v*v;
    }
    nrm = sqrtf(nrm);
    bf16h* crow = catb + (size_t)i*OUTD;
    crow[192 + 0*96 + t] = __float2bfloat16(loc[0]);
    crow[192 + 1*96 + t] = __float2bfloat16(loc[1]);
    crow[192 + 2*96 + t] = __float2bfloat16(loc[2]);
    crow[480 + t]        = __float2bfloat16(nrm);
  }
}

// ---------------- Kernel F: out = catb @ WoutT^T + bout via MFMA ----------------
__global__ __launch_bounds__(256) void k_out_mfma(
    const float* __restrict__ bout, const float* __restrict__ ws_c, float* __restrict__ out)
{
  const bf16h* catb  = (const bf16h*)(ws_c + OFF_CATB);
  const bf16h* woutT = (const bf16h*)(ws_c + OFF_WOT);
  const int t = threadIdx.x;
  const int wave = t >> 6, lane = t & 63;
  const int m0 = blockIdx.x*32 + (wave>>1)*16;
  const int n0 = blockIdx.y*32 + (wave&1)*16;
  const int lm = lane & 15, quad = lane >> 4;
  const bf16x8* pa = (const bf16x8*)(catb  + (size_t)(m0+lm)*OUTD) + quad;
  const bf16x8* pb = (const bf16x8*)(woutT + (size_t)(n0+lm)*OUTD) + quad;
  f32x4 acc = {0.f, 0.f, 0.f, 0.f};
  #pragma unroll 4
  for (int kk = 0; kk < OUTD/32; ++kk) {
    bf16x8 av = pa[kk*4];
    bf16x8 bv = pb[kk*4];
    acc = __builtin_amdgcn_mfma_f32_16x16x32_bf16(av, bv, acc, 0, 0, 0);
  }
  const int col = n0 + lm;
  const float bb = bout[col];
  #pragma unroll
  for (int r = 0; r < 4; ++r) {
    int row = m0 + quad*4 + r;
    out[(size_t)row*CSD + col] = acc[r] + bb;
  }
}

extern "C" void kernel_launch(void* const* d_in, const int* in_sizes, int n_in,
                              void* d_out, int out_size, void* d_ws, size_t ws_size,
                              hipStream_t stream)
{
  const float* s     = (const float*)d_in[0];
  const float* z     = (const float*)d_in[1];
  const float* rot   = (const float*)d_in[2];
  const float* trans = (const float*)d_in[3];
  const float* mask  = (const float*)d_in[4];
  const float* Wq    = (const float*)d_in[5];
  const float* bq    = (const float*)d_in[6];
  const float* Wkv   = (const float*)d_in[7];
  const float* bkv   = (const float*)d_in[8];
  const float* Wqp   = (const float*)d_in[9];
  const float* bqp   = (const float*)d_in[10];
  const float* Wkvp  = (const float*)d_in[11];
  const float* bkvp  = (const float*)d_in[12];
  const float* Wb    = (const float*)d_in[13];
  const float* bb    = (const float*)d_in[14];
  const float* hwts  = (const float*)d_in[15];
  const float* Wout  = (const float*)d_in[16];
  const float* bout  = (const float*)d_in[17];
  float* ws  = (float*)d_ws;
  float* out = (float*)d_out;

  hipLaunchKernelGGL(k_wcat, dim3(NPROJ + 128 + 1), dim3(256), 0, stream,
                     s, Wq, bq, Wkv, bkv, Wqp, bqp, Wkvp, bkvp, ws);
  hipLaunchKernelGGL(k_wtrans, dim3(CSD/32, OUTD/32), dim3(256), 0, stream, Wout, ws);
  hipLaunchKernelGGL(k_proj_gemm, dim3(NN/32, NPROJ/32), dim3(256), 0, stream, ws);
  hipLaunchKernelGGL(k_proj_epi,  dim3(NN/RPB), dim3(256), 0, stream, rot, trans, ws);
  hipLaunchKernelGGL(k_bpair, dim3(NN/64, NN), dim3(256), 0, stream, z, Wb, bb, ws);
  hipLaunchKernelGGL(k_attn,  dim3(NN, 3),     dim3(256), 0, stream, mask, hwts, ws);
  hipLaunchKernelGGL(k_opair, dim3(4, NN),     dim3(256), 0, stream, z, ws);
  hipLaunchKernelGGL(k_oacc,  dim3(NN),        dim3(512), 0, stream, rot, trans, ws);
  hipLaunchKernelGGL(k_out_mfma, dim3(NN/32, CSD/32), dim3(256), 0, stream, bout, ws, out);
}